// Round 1
// baseline (19828.888 us; speedup 1.0000x reference)
//
#include <hip/hip_runtime.h>
#include <hip/hip_cooperative_groups.h>

namespace cg = cooperative_groups;

typedef __attribute__((ext_vector_type(8))) short short8;
typedef __attribute__((ext_vector_type(4))) float f32x4;

// Workspace layout (bytes)
#define WS_XB     0ull          // x in bf16: [64][512][512]            33,554,432 B
#define WS_W0T    33554432ull   // layer0 weights^T fused: [4096][1536] 12,582,912 B
#define WS_W1T    46137344ull   // layer1 weights^T fused: [4096][2048] 16,777,216 B
#define WS_RING0  62914560ull   // h0 ring: [2][64][1024] bf16             262,144 B
#define WS_RING1  63176704ull   // h1 ring: [2][64][1024] bf16             262,144 B

__device__ __forceinline__ unsigned short f2bf(float f) {
  unsigned u = __float_as_uint(f);
  u += 0x7FFFu + ((u >> 16) & 1u);   // round-to-nearest-even
  return (unsigned short)(u >> 16);
}

__device__ __forceinline__ float sigm(float x) { return 1.0f / (1.0f + __expf(-x)); }

// ---- prep: fp32 -> bf16 copy of x (4 elems/thread) ----
__global__ void convert_x_kernel(const float* __restrict__ x, unsigned short* __restrict__ xb) {
  int i = blockIdx.x * 256 + threadIdx.x;
  const float4 v = ((const float4*)x)[i];
  unsigned long long pack = (unsigned long long)f2bf(v.x)
                          | ((unsigned long long)f2bf(v.y) << 16)
                          | ((unsigned long long)f2bf(v.z) << 32)
                          | ((unsigned long long)f2bf(v.w) << 48);
  ((unsigned long long*)xb)[i] = pack;
}

// ---- prep: transpose [K][4096] fp32 (Wx stacked over Wh) -> [4096 perm][Ktot] bf16 ----
// Output row r = unit*4 + gate  (unit = n % 1024, gate = n / 1024) so each WG's
// 32 rows are contiguous and unit-major.
__global__ void transpose_weights_kernel(const float* __restrict__ wx, const float* __restrict__ wh,
                                         unsigned short* __restrict__ dst, int Kx, int Ktot) {
  __shared__ float tile[32][33];
  const int k0 = blockIdx.x * 32, n0 = blockIdx.y * 32;
  const int tx = threadIdx.x, ty = threadIdx.y;
#pragma unroll
  for (int i = 0; i < 4; ++i) {
    int k = k0 + ty + i * 8;
    tile[ty + i * 8][tx] = (k < Kx) ? wx[(size_t)k * 4096 + n0 + tx]
                                    : wh[(size_t)(k - Kx) * 4096 + n0 + tx];
  }
  __syncthreads();
#pragma unroll
  for (int i = 0; i < 4; ++i) {
    int n = n0 + ty + i * 8;
    int r = (n & 1023) * 4 + (n >> 10);
    dst[(size_t)r * Ktot + k0 + tx] = f2bf(tile[tx][ty + i * 8]);
  }
}

// ---- persistent fused 2-layer LSTM ----
// grid = 256 WGs (1/CU). WGs [0,128): layer0; WGs [128,256): layer1, one step behind.
// Each WG: 8 hidden units -> 32 gate columns; weight slice [32][K] bf16 resident in LDS
// (K-stride padded +8 to break bank conflicts). 4 waves = 4 batch tiles of 16.
// MFMA 16x16x32 with A = weight rows (M=gate cols), B = xcat (N=batch):
// lane's 4 acc regs = gates {i,f,g,o} of one (batch,unit) pair -> lane-local cell update.
__global__ void __launch_bounds__(256, 1) lstm_persistent(
    const unsigned short* __restrict__ xb,
    const unsigned short* __restrict__ w0t,
    const unsigned short* __restrict__ w1t,
    const float* __restrict__ b0v, const float* __restrict__ b1v,
    unsigned short* __restrict__ ring0, unsigned short* __restrict__ ring1,
    float* __restrict__ out)
{
  extern __shared__ unsigned short lds[];
  cg::grid_group grid = cg::this_grid();

  const int wg    = blockIdx.x;
  const int group = wg >> 7;       // 0: layer0, 1: layer1
  const int wgl   = wg & 127;
  const int hu0   = wgl * 8;
  const int tid   = threadIdx.x;
  const int lane  = tid & 63;
  const int wid   = tid >> 6;
  const int c16   = lane & 15;     // A-row / B-col within tile
  const int row4  = lane >> 4;     // k-subgroup; also acc row-group
  const int bb    = wid * 16 + c16; // this lane's batch (as C-col)

  const int K    = group ? 2048 : 1536;
  const int KPAD = group ? 2056 : 1544;

  { // stage weight slice global -> LDS (padded rows)
    const unsigned short* wsrc = (group ? w1t : w0t) + (size_t)(wgl * 32) * K;
    const int kv = K >> 3;
    for (int c = tid; c < 32 * kv; c += 256) {
      int r = c / kv, q = c - r * kv;
      *(short8*)&lds[r * KPAD + q * 8] = *(const short8*)&wsrc[(size_t)r * K + q * 8];
    }
  }
  __syncthreads();

  const float* bsrc = group ? b1v : b0v;
  float bias0[4], bias1[4];
#pragma unroll
  for (int j = 0; j < 4; ++j) {
    bias0[j] = bsrc[j * 1024 + hu0 + row4];       // tile0: unit = hu0 + row4
    bias1[j] = bsrc[j * 1024 + hu0 + 4 + row4];   // tile1: unit = hu0 + 4 + row4
  }

  const int a0b = c16 * KPAD + 8 * row4;          // LDS elem offset of A-frag, tile0
  const int a1b = a0b + 16 * KPAD;                // tile1 (+16 rows)

  float cst0 = 0.0f, cst1 = 0.0f;

  for (int s = 0; s <= 512; ++s) {
    const int rd = (s - 1) & 1, wr = s & 1;
    const bool active = group ? (s >= 1) : (s < 512);
    if (active) {
      const int t = group ? (s - 1) : s;

      f32x4 acc0 = { bias0[0], bias0[1], bias0[2], bias0[3] };
      f32x4 acc1 = { bias1[0], bias1[1], bias1[2], bias1[3] };

      // Region pointers (per-lane): region1 then region2 are contiguous in k.
      const unsigned short* r1p;
      const unsigned short* r2p;
      int n1;                                        // 256-k blocks in region1
      if (group == 0) {
        r1p = xb + ((size_t)bb << 18) + (size_t)t * 512 + 8 * row4;  // x[t]
        r2p = ring0 + (rd << 16) + (bb << 10) + 8 * row4;            // h0[t-1]
        n1 = 2;                                                      // 512 k
      } else {
        r1p = ring0 + (rd << 16) + (bb << 10) + 8 * row4;            // h0[t]
        r2p = ring1 + (rd << 16) + (bb << 10) + 8 * row4;            // h1[t-1]
        n1 = 4;                                                      // 1024 k
      }
      const int nblk = n1 + 4;                                       // + 1024 k

      auto loadB = [&](short8* dst, int blk) {
        const unsigned short* p = (blk < n1) ? (r1p + blk * 256) : (r2p + (blk - n1) * 256);
#pragma unroll
        for (int j = 0; j < 8; ++j) dst[j] = *(const short8*)(p + j * 32);
      };
      auto compute8 = [&](const short8* bfr, int kg) {
#pragma unroll
        for (int j = 0; j < 8; ++j) {
          const int ko = kg + j * 32;
          short8 a0 = *(const short8*)&lds[a0b + ko];
          short8 a1 = *(const short8*)&lds[a1b + ko];
          acc0 = __builtin_amdgcn_mfma_f32_16x16x32_bf16(a0, bfr[j], acc0, 0, 0, 0);
          acc1 = __builtin_amdgcn_mfma_f32_16x16x32_bf16(a1, bfr[j], acc1, 0, 0, 0);
        }
      };

      short8 bA[8], bB[8];
      loadB(bA, 0);
      for (int bp = 0; bp < nblk; bp += 2) {         // nblk is even (6 or 8)
        loadB(bB, bp + 1);
        compute8(bA, bp * 256);
        if (bp + 2 < nblk) loadB(bA, bp + 2);
        compute8(bB, (bp + 1) * 256);
      }

      // Gate math: reg j of each acc = gate j (i,f,g,o) for this lane's (batch,unit).
      unsigned short* rw = (group ? ring1 : ring0) + (wr << 16) + (bb << 10) + hu0 + row4;
      {
        float iv = sigm(acc0[0]), fv = sigm(acc0[1]);
        float gv = tanhf(acc0[2]), ov = sigm(acc0[3]);
        cst0 = fv * cst0 + iv * gv;
        float hv = ov * tanhf(cst0);
        rw[0] = f2bf(hv);
        if (group) out[((size_t)bb << 19) + ((size_t)t << 10) + hu0 + row4] = hv;
      }
      {
        float iv = sigm(acc1[0]), fv = sigm(acc1[1]);
        float gv = tanhf(acc1[2]), ov = sigm(acc1[3]);
        cst1 = fv * cst1 + iv * gv;
        float hv = ov * tanhf(cst1);
        rw[4] = f2bf(hv);
        if (group) out[((size_t)bb << 19) + ((size_t)t << 10) + hu0 + 4 + row4] = hv;
      }
    }
    grid.sync();
  }
}

extern "C" void kernel_launch(void* const* d_in, const int* in_sizes, int n_in,
                              void* d_out, int out_size, void* d_ws, size_t ws_size,
                              hipStream_t stream) {
  const float* x   = (const float*)d_in[0];
  const float* Wx0 = (const float*)d_in[1];
  const float* Wh0 = (const float*)d_in[2];
  const float* b0  = (const float*)d_in[3];
  const float* Wx1 = (const float*)d_in[4];
  const float* Wh1 = (const float*)d_in[5];
  const float* b1  = (const float*)d_in[6];
  float* outp = (float*)d_out;

  char* ws = (char*)d_ws;
  unsigned short* xbp   = (unsigned short*)(ws + WS_XB);
  unsigned short* w0tp  = (unsigned short*)(ws + WS_W0T);
  unsigned short* w1tp  = (unsigned short*)(ws + WS_W1T);
  unsigned short* ring0 = (unsigned short*)(ws + WS_RING0);
  unsigned short* ring1 = (unsigned short*)(ws + WS_RING1);

  // prep
  convert_x_kernel<<<dim3(16384), dim3(256), 0, stream>>>(x, xbp);
  transpose_weights_kernel<<<dim3(48, 128), dim3(32, 8), 0, stream>>>(Wx0, Wh0, w0tp, 512, 1536);
  transpose_weights_kernel<<<dim3(64, 128), dim3(32, 8), 0, stream>>>(Wx1, Wh1, w1tp, 1024, 2048);
  hipMemsetAsync(ring0, 0, 524288, stream);  // both rings (contiguous): h(-1) = 0

  // persistent fused kernel, cooperative (grid.sync per time step)
  void* kargs[] = { (void*)&xbp, (void*)&w0tp, (void*)&w1tp, (void*)&b0, (void*)&b1,
                    (void*)&ring0, (void*)&ring1, (void*)&outp };
  hipLaunchCooperativeKernel((void*)lstm_persistent, dim3(256), dim3(256),
                             kargs, 32 * 2056 * 2 /* 131,584 B LDS */, stream);
}

// Round 7
// 8048.264 us; speedup vs baseline: 2.4637x; 2.4637x over previous
//
#include <hip/hip_runtime.h>

typedef __attribute__((ext_vector_type(8))) short short8;
typedef __attribute__((ext_vector_type(4))) float f32x4;

// Workspace layout (bytes)
#define WS_XB     0ull          // x in bf16: [64][512][512]            33,554,432 B
#define WS_W0T    33554432ull   // layer0 weights^T fused: [4096][1536] 12,582,912 B
#define WS_W1T    46137344ull   // layer1 weights^T fused: [4096][2048] 16,777,216 B
#define WS_RING0  62914560ull   // h0 ring: [32][64][1024] bf16           4,194,304 B
#define WS_RING1  67108864ull   // h1 ring: [32][64][1024] bf16           4,194,304 B
#define WS_BAR    71303168ull   // barrier counters: 16 group lines + root    4,096 B
#define SLOT_ELEMS 65536        // 64 batches x 1024 units per ring slot
#define SLOT_BYTES 131072

__device__ __forceinline__ unsigned short f2bf(float f) {
  unsigned u = __float_as_uint(f);
  u += 0x7FFFu + ((u >> 16) & 1u);   // round-to-nearest-even
  return (unsigned short)(u >> 16);
}

__device__ __forceinline__ float sigm(float x) { return 1.0f / (1.0f + __expf(-x)); }

// ---- sentinel: "persistent kernel never ran" (absmax ~1e6) vs
// ---- "h never flowed" (absmax 0.402). Overwritten by the persistent kernel.
__global__ void sentinel_kernel(float* out) { out[0] = 1.0e6f; }

// ---- prep: fp32 -> bf16 copy of x (4 elems/thread) ----
__global__ void convert_x_kernel(const float* __restrict__ x, unsigned short* __restrict__ xb) {
  int i = blockIdx.x * 256 + threadIdx.x;
  const float4 v = ((const float4*)x)[i];
  unsigned long long pack = (unsigned long long)f2bf(v.x)
                          | ((unsigned long long)f2bf(v.y) << 16)
                          | ((unsigned long long)f2bf(v.z) << 32)
                          | ((unsigned long long)f2bf(v.w) << 48);
  ((unsigned long long*)xb)[i] = pack;
}

// ---- prep: transpose [K][4096] fp32 (Wx stacked over Wh) -> [4096 perm][Ktot] bf16 ----
// Output row r = unit*4 + gate so each WG's 32 rows are contiguous, unit-major.
__global__ void transpose_weights_kernel(const float* __restrict__ wx, const float* __restrict__ wh,
                                         unsigned short* __restrict__ dst, int Kx, int Ktot) {
  __shared__ float tile[32][33];
  const int k0 = blockIdx.x * 32, n0 = blockIdx.y * 32;
  const int tx = threadIdx.x, ty = threadIdx.y;
#pragma unroll
  for (int i = 0; i < 4; ++i) {
    int k = k0 + ty + i * 8;
    tile[ty + i * 8][tx] = (k < Kx) ? wx[(size_t)k * 4096 + n0 + tx]
                                    : wh[(size_t)(k - Kx) * 4096 + n0 + tx];
  }
  __syncthreads();
#pragma unroll
  for (int i = 0; i < 4; ++i) {
    int n = n0 + ty + i * 8;
    int r = (n & 1023) * 4 + (n >> 10);
    dst[(size_t)r * Ktot + k0 + tx] = f2bf(tile[tx][ty + i * 8]);
  }
}

// ---- per-step MFMA micro-kernel ----
// FIXED pipeline (R2-R6 bug): compute slot bp&3 FIRST, then prefetch block
// bp+4 into the just-freed slot. (The old order clobbered block bp with
// block bp+4 before it was consumed, which erased the x contribution and
// made the whole recurrence identically zero.)
template<int N1, int NBLK>
__device__ __forceinline__ void lstm_step_mfma(int a0b, int a1b,
    const unsigned short* __restrict__ r1p, const unsigned short* __restrict__ r2p,
    f32x4& acc0, f32x4& acc1)
{
  extern __shared__ unsigned short lds[];
  short8 buf[4][8];

  auto loadB = [&](int slot, int blk) {
    const unsigned short* p = (blk < N1) ? (r1p + blk * 256) : (r2p + (blk - N1) * 256);
#pragma unroll
    for (int j = 0; j < 8; ++j) buf[slot][j] = *(const short8*)(p + j * 32);
  };
  auto compute8 = [&](int slot, int kg) {
#pragma unroll
    for (int j = 0; j < 8; ++j) {
      const int ko = kg + j * 32;
      short8 a0 = *(const short8*)&lds[a0b + ko];
      short8 a1 = *(const short8*)&lds[a1b + ko];
      acc0 = __builtin_amdgcn_mfma_f32_16x16x32_bf16(a0, buf[slot][j], acc0, 0, 0, 0);
      acc1 = __builtin_amdgcn_mfma_f32_16x16x32_bf16(a1, buf[slot][j], acc1, 0, 0, 0);
    }
  };

  loadB(0, 0); loadB(1, 1); loadB(2, 2); loadB(3, 3);
#pragma unroll
  for (int bp = 0; bp < NBLK; ++bp) {
    compute8(bp & 3, bp * 256);                      // consume block bp
    if (bp + 4 < NBLK) loadB(bp & 3, bp + 4);        // then refill the slot
  }
}

// ---- persistent fused 2-layer LSTM ----
// 256 WGs (1/CU). WGs [0,128): layer0; [128,256): layer1 one step behind.
// Weights LDS-resident.
// Cross-block h exchange (belt + suspenders, either alone should suffice):
//   * writes (h rings, out) = atomic EXCHANGE -> execute at the coherence
//     point (RMW class proven cross-XCD by the barrier itself); no line is
//     ever dirty in any L2.
//   * reads = plain vector loads, kept fresh by BOTH (a) depth-32 ring:
//     ~320KB/XCD/step of traffic capacity-evicts consumer L1+L2 lines long
//     before slot reuse 32 steps later, and (b) explicit per-step
//     `buffer_inv sc1` after the barrier (safe: nothing dirty anywhere).
__global__ void __launch_bounds__(256, 1) lstm_persistent(
    const unsigned short* __restrict__ xb,
    const unsigned short* __restrict__ w0t,
    const unsigned short* __restrict__ w1t,
    const float* __restrict__ b0v, const float* __restrict__ b1v,
    unsigned short* __restrict__ ring0, unsigned short* __restrict__ ring1,
    unsigned* __restrict__ bar,
    float* __restrict__ out)
{
  extern __shared__ unsigned short lds[];

  const int wg    = blockIdx.x;
  const int group = wg >> 7;       // 0: layer0, 1: layer1
  const int wgl   = wg & 127;
  const int hu0   = wgl * 8;
  const int tid   = threadIdx.x;
  const int lane  = tid & 63;
  const int wid   = tid >> 6;
  const int c16   = lane & 15;
  const int row4  = lane >> 4;
  const int bb    = wid * 16 + c16; // this lane's batch

  const int K    = group ? 2048 : 1536;
  const int KPAD = group ? 2056 : 1544;

  { // stage weight slice global -> LDS, permuted: LDS row r <- slice row
    // src(r) = 8*((r&15)>>2) + 4*(r>>4) + (r&3)  (tile0 even-of-pair, tile1 odd)
    const unsigned short* wsrc = (group ? w1t : w0t) + (size_t)(wgl * 32) * K;
    const int kv = K >> 3;
    for (int c = tid; c < 32 * kv; c += 256) {
      int r = c / kv, q = c - r * kv;
      int srcr = 8 * ((r & 15) >> 2) + 4 * (r >> 4) + (r & 3);
      *(short8*)&lds[r * KPAD + q * 8] = *(const short8*)&wsrc[(size_t)srcr * K + q * 8];
    }
  }
  __syncthreads();

  const float* bsrc = group ? b1v : b0v;
  float bias0[4], bias1[4];
#pragma unroll
  for (int j = 0; j < 4; ++j) {
    bias0[j] = bsrc[j * 1024 + hu0 + 2 * row4];       // even unit of pair
    bias1[j] = bsrc[j * 1024 + hu0 + 2 * row4 + 1];   // odd unit of pair
  }

  const int a0b = c16 * KPAD + 8 * row4;
  const int a1b = a0b + 16 * KPAD;

  const int lofs = (bb << 10) + 8 * row4;              // read offset within a slot
  const unsigned short* x_cur = xb + ((size_t)bb << 18) + 8 * row4;  // +512/step
  unsigned* rwb = (unsigned*)(group ? ring1 : ring0) + (((bb << 10) + hu0) >> 1) + row4;
  float* out_base = out + ((size_t)bb << 19) + hu0 + 2 * row4;

  // Barrier bookkeeping: 16 groups of 16 blocks; 128B-spaced counter lines.
  unsigned* grpc  = bar + ((wg >> 4) << 5);
  unsigned* rootc = bar + (16 << 5);

  float cst0 = 0.0f, cst1 = 0.0f;

  for (int s = 0; s <= 512; ++s) {
    const bool active = group ? (s >= 1) : (s < 512);
    if (active) {
      const int t = group ? (s - 1) : s;

      f32x4 acc0 = { bias0[0], bias0[1], bias0[2], bias0[3] };
      f32x4 acc1 = { bias1[0], bias1[1], bias1[2], bias1[3] };

      const unsigned short* h0rd = ring0 + ((s - 1) & 31) * SLOT_ELEMS + lofs;  // h0[s-1]
      if (group == 0) {
        lstm_step_mfma<2, 6>(a0b, a1b, x_cur, h0rd, acc0, acc1);
        x_cur += 512;
      } else {
        const unsigned short* h1rd = ring1 + ((s - 2) & 31) * SLOT_ELEMS + lofs; // h1[s-2]
        lstm_step_mfma<4, 8>(a0b, a1b, h0rd, h1rd, acc0, acc1);
      }

      float hv0, hv1;
      {
        float iv = sigm(acc0[0]), fv = sigm(acc0[1]);
        float gv = tanhf(acc0[2]), ov = sigm(acc0[3]);
        cst0 = fv * cst0 + iv * gv;
        hv0 = ov * tanhf(cst0);
      }
      {
        float iv = sigm(acc1[0]), fv = sigm(acc1[1]);
        float gv = tanhf(acc1[2]), ov = sigm(acc1[3]);
        cst1 = fv * cst1 + iv * gv;
        hv1 = ov * tanhf(cst1);
      }
      // h write: RMW exchange -> coherence point; slot t&31.
      unsigned hp = (unsigned)f2bf(hv0) | ((unsigned)f2bf(hv1) << 16);
      (void)__hip_atomic_exchange(rwb + (t & 31) * (SLOT_ELEMS / 2), hp,
                                  __ATOMIC_RELAXED, __HIP_MEMORY_SCOPE_AGENT);
      if (group) {
        // out write: u64 RMW exchange of the packed float2 (same reason).
        union { float2 f; unsigned long long u; } o;
        o.f.x = hv0; o.f.y = hv1;
        (void)__hip_atomic_exchange((unsigned long long*)(out_base + ((size_t)t << 10)),
                                    o.u, __ATOMIC_RELAXED, __HIP_MEMORY_SCOPE_AGENT);
      }
    }

    // ---- grid barrier (episode s) + post-barrier invalidate ----
    // __syncthreads drains each wave's vmem (exchanges at MALL) before tid0
    // arrives; after the spin, ALL blocks' step-s data is at the coherence
    // point and nothing is dirty anywhere -> safe to invalidate local caches.
    __syncthreads();
    if (tid == 0) {
      unsigned old = __hip_atomic_fetch_add(grpc, 1u, __ATOMIC_RELAXED, __HIP_MEMORY_SCOPE_AGENT);
      if (old == (unsigned)(16 * (s + 1) - 1))
        __hip_atomic_fetch_add(rootc, 1u, __ATOMIC_RELAXED, __HIP_MEMORY_SCOPE_AGENT);
      const unsigned tgt = (unsigned)(16 * (s + 1));
      while (__hip_atomic_load(rootc, __ATOMIC_RELAXED, __HIP_MEMORY_SCOPE_AGENT) < tgt)
        __builtin_amdgcn_s_sleep(2);
      asm volatile("buffer_inv sc1\n\ts_waitcnt vmcnt(0)" ::: "memory");
    }
    __syncthreads();   // no wave reads until tid0's invalidate completed
  }
}

extern "C" void kernel_launch(void* const* d_in, const int* in_sizes, int n_in,
                              void* d_out, int out_size, void* d_ws, size_t ws_size,
                              hipStream_t stream) {
  const float* x   = (const float*)d_in[0];
  const float* Wx0 = (const float*)d_in[1];
  const float* Wh0 = (const float*)d_in[2];
  const float* b0  = (const float*)d_in[3];
  const float* Wx1 = (const float*)d_in[4];
  const float* Wh1 = (const float*)d_in[5];
  const float* b1  = (const float*)d_in[6];
  float* outp = (float*)d_out;

  char* ws = (char*)d_ws;
  unsigned short* xbp   = (unsigned short*)(ws + WS_XB);
  unsigned short* w0tp  = (unsigned short*)(ws + WS_W0T);
  unsigned short* w1tp  = (unsigned short*)(ws + WS_W1T);
  unsigned short* ring0 = (unsigned short*)(ws + WS_RING0);
  unsigned short* ring1 = (unsigned short*)(ws + WS_RING1);
  unsigned*       barp  = (unsigned*)(ws + WS_BAR);

  // prep
  sentinel_kernel<<<dim3(1), dim3(1), 0, stream>>>(outp);
  convert_x_kernel<<<dim3(16384), dim3(256), 0, stream>>>(x, xbp);
  transpose_weights_kernel<<<dim3(48, 128), dim3(32, 8), 0, stream>>>(Wx0, Wh0, w0tp, 512, 1536);
  transpose_weights_kernel<<<dim3(64, 128), dim3(32, 8), 0, stream>>>(Wx1, Wh1, w1tp, 1024, 2048);
  // zero the t=-1 slots (slot 31 of each ring) + barrier counters
  hipMemsetAsync(ring0 + 31 * SLOT_ELEMS, 0, SLOT_BYTES, stream);
  hipMemsetAsync(ring1 + 31 * SLOT_ELEMS, 0, SLOT_BYTES, stream);
  hipMemsetAsync(barp, 0, 4096, stream);

  // persistent fused kernel; prefer cooperative launch, fall back to a plain
  // launch (256 blocks x 1 block/CU is co-resident on 256 CUs) if it fails.
  void* kargs[] = { (void*)&xbp, (void*)&w0tp, (void*)&w1tp, (void*)&b0, (void*)&b1,
                    (void*)&ring0, (void*)&ring1, (void*)&barp, (void*)&outp };
  hipError_t e = hipLaunchCooperativeKernel((void*)lstm_persistent, dim3(256), dim3(256),
                                            kargs, 32 * 2056 * 2 /* 131,584 B LDS */, stream);
  if (e != hipSuccess) {
    lstm_persistent<<<dim3(256), dim3(256), 32 * 2056 * 2, stream>>>(
        xbp, w0tp, w1tp, b0, b1, ring0, ring1, barp, outp);
  }
}

// Round 8
// 5194.962 us; speedup vs baseline: 3.8169x; 1.5492x over previous
//
#include <hip/hip_runtime.h>

typedef __attribute__((ext_vector_type(8))) short short8;
typedef __attribute__((ext_vector_type(4))) float f32x4;

// Workspace layout (bytes)
#define WS_XB     0ull          // x in bf16: [64][512][512]            33,554,432 B
#define WS_W0T    33554432ull   // layer0 weights^T fused: [4096][1536] 12,582,912 B
#define WS_W1T    46137344ull   // layer1 weights^T fused: [4096][2048] 16,777,216 B
#define WS_RING0  62914560ull   // h0 ring: [32][64][1024] bf16           4,194,304 B
#define WS_RING1  67108864ull   // h1 ring: [32][64][1024] bf16           4,194,304 B
#define WS_BAR    71303168ull   // barrier counters (<=4096 B used)
#define SLOT_ELEMS 65536        // 64 batches x 1024 units per ring slot
#define SLOT_BYTES 131072

// Barrier word offsets (x4 B): arrive[g]=g*16, root=256, release[g]=272+g*16
#define BAR_ARR(g)  ((g) * 16)
#define BAR_ROOT    256
#define BAR_REL(g)  (272 + (g) * 16)

__device__ __forceinline__ unsigned short f2bf(float f) {
  unsigned u = __float_as_uint(f);
  u += 0x7FFFu + ((u >> 16) & 1u);   // round-to-nearest-even
  return (unsigned short)(u >> 16);
}

__device__ __forceinline__ float sigm(float x) { return 1.0f / (1.0f + __expf(-x)); }

// ---- sentinel: "persistent kernel never ran" (absmax ~1e6) marker ----
__global__ void sentinel_kernel(float* out) { out[0] = 1.0e6f; }

// ---- prep: fp32 -> bf16 copy of x (4 elems/thread) ----
__global__ void convert_x_kernel(const float* __restrict__ x, unsigned short* __restrict__ xb) {
  int i = blockIdx.x * 256 + threadIdx.x;
  const float4 v = ((const float4*)x)[i];
  unsigned long long pack = (unsigned long long)f2bf(v.x)
                          | ((unsigned long long)f2bf(v.y) << 16)
                          | ((unsigned long long)f2bf(v.z) << 32)
                          | ((unsigned long long)f2bf(v.w) << 48);
  ((unsigned long long*)xb)[i] = pack;
}

// ---- prep: transpose [K][4096] fp32 (Wx stacked over Wh) -> [4096 perm][Ktot] bf16 ----
__global__ void transpose_weights_kernel(const float* __restrict__ wx, const float* __restrict__ wh,
                                         unsigned short* __restrict__ dst, int Kx, int Ktot) {
  __shared__ float tile[32][33];
  const int k0 = blockIdx.x * 32, n0 = blockIdx.y * 32;
  const int tx = threadIdx.x, ty = threadIdx.y;
#pragma unroll
  for (int i = 0; i < 4; ++i) {
    int k = k0 + ty + i * 8;
    tile[ty + i * 8][tx] = (k < Kx) ? wx[(size_t)k * 4096 + n0 + tx]
                                    : wh[(size_t)(k - Kx) * 4096 + n0 + tx];
  }
  __syncthreads();
#pragma unroll
  for (int i = 0; i < 4; ++i) {
    int n = n0 + ty + i * 8;
    int r = (n & 1023) * 4 + (n >> 10);
    dst[(size_t)r * Ktot + k0 + tx] = f2bf(tile[tx][ty + i * 8]);
  }
}

// ---- per-step MFMA micro-kernel: 4-deep pipeline PINNED with sched_barrier ----
// R7 showed VGPR=36: the compiler collapsed the pipeline by sinking loads to
// their consumers. sched_barrier(0) after each load-issue point forbids that:
// 4 blocks (32 x 16B loads) stay in flight, hiding L2/MALL latency.
template<int N1, int NBLK>
__device__ __forceinline__ void lstm_step_mfma(int a0b, int a1b,
    const unsigned short* __restrict__ r1p, const unsigned short* __restrict__ r2p,
    f32x4& acc0, f32x4& acc1)
{
  extern __shared__ unsigned short lds[];
  short8 buf[4][8];

  auto loadB = [&](int slot, int blk) {
    const unsigned short* p = (blk < N1) ? (r1p + blk * 256) : (r2p + (blk - N1) * 256);
#pragma unroll
    for (int j = 0; j < 8; ++j) buf[slot][j] = *(const short8*)(p + j * 32);
  };
  auto compute8 = [&](int slot, int kg) {
#pragma unroll
    for (int j = 0; j < 8; ++j) {
      const int ko = kg + j * 32;
      short8 a0 = *(const short8*)&lds[a0b + ko];
      short8 a1 = *(const short8*)&lds[a1b + ko];
      acc0 = __builtin_amdgcn_mfma_f32_16x16x32_bf16(a0, buf[slot][j], acc0, 0, 0, 0);
      acc1 = __builtin_amdgcn_mfma_f32_16x16x32_bf16(a1, buf[slot][j], acc1, 0, 0, 0);
    }
  };

  loadB(0, 0); loadB(1, 1); loadB(2, 2); loadB(3, 3);
  __builtin_amdgcn_sched_barrier(0);            // all 4 blocks issued before any compute
#pragma unroll
  for (int bp = 0; bp < NBLK; ++bp) {
    compute8(bp & 3, bp * 256);                 // consume block bp
    if (bp + 4 < NBLK) loadB(bp & 3, bp + 4);   // refill the freed slot
    __builtin_amdgcn_sched_barrier(0);          // refill may not sink into later iters
  }
}

// ---- persistent fused 2-layer LSTM ----
// 256 WGs (1/CU). WGs [0,128): layer0; [128,256): layer1 one step behind.
// Weights LDS-resident.
// Coherence: h/out writes = atomic exchange (RMW -> coherence point; no dirty
// L2 lines anywhere). h reads = plain cached loads, fresh by capacity
// eviction: depth-32 rings mean a slot's address was last cached 32 episodes
// (~16 MB of per-XCD L2 traffic, 4x capacity) before reuse. No buffer_inv:
// x and broadcast h reads stay L2-shared across the XCD's 32 WGs.
__global__ void __launch_bounds__(256, 1) lstm_persistent(
    const unsigned short* __restrict__ xb,
    const unsigned short* __restrict__ w0t,
    const unsigned short* __restrict__ w1t,
    const float* __restrict__ b0v, const float* __restrict__ b1v,
    unsigned short* __restrict__ ring0, unsigned short* __restrict__ ring1,
    unsigned* __restrict__ bar,
    float* __restrict__ out)
{
  extern __shared__ unsigned short lds[];

  const int wg    = blockIdx.x;
  const int group = wg >> 7;       // 0: layer0, 1: layer1
  const int wgl   = wg & 127;
  const int hu0   = wgl * 8;
  const int tid   = threadIdx.x;
  const int lane  = tid & 63;
  const int wid   = tid >> 6;
  const int c16   = lane & 15;
  const int row4  = lane >> 4;
  const int bb    = wid * 16 + c16; // this lane's batch

  const int K    = group ? 2048 : 1536;
  const int KPAD = group ? 2056 : 1544;

  { // stage weight slice global -> LDS, permuted: LDS row r <- slice row
    // src(r) = 8*((r&15)>>2) + 4*(r>>4) + (r&3)  (tile0 even-of-pair, tile1 odd)
    const unsigned short* wsrc = (group ? w1t : w0t) + (size_t)(wgl * 32) * K;
    const int kv = K >> 3;
    for (int c = tid; c < 32 * kv; c += 256) {
      int r = c / kv, q = c - r * kv;
      int srcr = 8 * ((r & 15) >> 2) + 4 * (r >> 4) + (r & 3);
      *(short8*)&lds[r * KPAD + q * 8] = *(const short8*)&wsrc[(size_t)srcr * K + q * 8];
    }
  }
  __syncthreads();

  const float* bsrc = group ? b1v : b0v;
  float bias0[4], bias1[4];
#pragma unroll
  for (int j = 0; j < 4; ++j) {
    bias0[j] = bsrc[j * 1024 + hu0 + 2 * row4];       // even unit of pair
    bias1[j] = bsrc[j * 1024 + hu0 + 2 * row4 + 1];   // odd unit of pair
  }

  const int a0b = c16 * KPAD + 8 * row4;
  const int a1b = a0b + 16 * KPAD;

  const int lofs = (bb << 10) + 8 * row4;              // read offset within a slot
  const unsigned short* x_cur = xb + ((size_t)bb << 18) + 8 * row4;  // +512/step
  unsigned* rwb = (unsigned*)(group ? ring1 : ring0) + (((bb << 10) + hu0) >> 1) + row4;
  float* out_base = out + ((size_t)bb << 19) + hu0 + 2 * row4;

  // Barrier: 16 groups of 16 blocks; separate arrive lines + release flags.
  const int mygrp = wg >> 4;
  unsigned* grpc  = bar + BAR_ARR(mygrp);
  unsigned* rootc = bar + BAR_ROOT;
  unsigned* relc  = bar + BAR_REL(mygrp);

  float cst0 = 0.0f, cst1 = 0.0f;

  for (int s = 0; s <= 512; ++s) {
    const bool active = group ? (s >= 1) : (s < 512);
    if (active) {
      const int t = group ? (s - 1) : s;

      f32x4 acc0 = { bias0[0], bias0[1], bias0[2], bias0[3] };
      f32x4 acc1 = { bias1[0], bias1[1], bias1[2], bias1[3] };

      const unsigned short* h0rd = ring0 + ((s - 1) & 31) * SLOT_ELEMS + lofs;  // h0[s-1]
      if (group == 0) {
        lstm_step_mfma<2, 6>(a0b, a1b, x_cur, h0rd, acc0, acc1);
        x_cur += 512;
      } else {
        const unsigned short* h1rd = ring1 + ((s - 2) & 31) * SLOT_ELEMS + lofs; // h1[s-2]
        lstm_step_mfma<4, 8>(a0b, a1b, h0rd, h1rd, acc0, acc1);
      }

      float hv0, hv1;
      {
        float iv = sigm(acc0[0]), fv = sigm(acc0[1]);
        float gv = tanhf(acc0[2]), ov = sigm(acc0[3]);
        cst0 = fv * cst0 + iv * gv;
        hv0 = ov * tanhf(cst0);
      }
      {
        float iv = sigm(acc1[0]), fv = sigm(acc1[1]);
        float gv = tanhf(acc1[2]), ov = sigm(acc1[3]);
        cst1 = fv * cst1 + iv * gv;
        hv1 = ov * tanhf(cst1);
      }
      // h write: RMW exchange -> coherence point; slot t&31.
      unsigned hp = (unsigned)f2bf(hv0) | ((unsigned)f2bf(hv1) << 16);
      (void)__hip_atomic_exchange(rwb + (t & 31) * (SLOT_ELEMS / 2), hp,
                                  __ATOMIC_RELAXED, __HIP_MEMORY_SCOPE_AGENT);
      if (group) {
        // out: plain store; dispatch-end L2 writeback makes it host-visible.
        float2 o2; o2.x = hv0; o2.y = hv1;
        *(float2*)(out_base + ((size_t)t << 10)) = o2;
      }
    }

    // ---- grid barrier (episode s): arrive tree + per-group release flags ----
    // __syncthreads drains each wave's vmem (exchanges at coherence point)
    // before tid0 arrives.
    __syncthreads();
    if (tid == 0) {
      unsigned old = __hip_atomic_fetch_add(grpc, 1u, __ATOMIC_RELAXED, __HIP_MEMORY_SCOPE_AGENT);
      if (old == (unsigned)(16 * s + 15)) {                 // group complete
        unsigned old2 = __hip_atomic_fetch_add(rootc, 1u, __ATOMIC_RELAXED, __HIP_MEMORY_SCOPE_AGENT);
        if (old2 == (unsigned)(16 * s + 15)) {              // globally last
#pragma unroll
          for (int g2 = 0; g2 < 16; ++g2)
            (void)__hip_atomic_exchange(bar + BAR_REL(g2), (unsigned)(s + 1),
                                        __ATOMIC_RELAXED, __HIP_MEMORY_SCOPE_AGENT);
        }
      }
      while (__hip_atomic_load(relc, __ATOMIC_RELAXED, __HIP_MEMORY_SCOPE_AGENT) < (unsigned)(s + 1))
        __builtin_amdgcn_s_sleep(1);
    }
    __syncthreads();
  }
}

extern "C" void kernel_launch(void* const* d_in, const int* in_sizes, int n_in,
                              void* d_out, int out_size, void* d_ws, size_t ws_size,
                              hipStream_t stream) {
  const float* x   = (const float*)d_in[0];
  const float* Wx0 = (const float*)d_in[1];
  const float* Wh0 = (const float*)d_in[2];
  const float* b0  = (const float*)d_in[3];
  const float* Wx1 = (const float*)d_in[4];
  const float* Wh1 = (const float*)d_in[5];
  const float* b1  = (const float*)d_in[6];
  float* outp = (float*)d_out;

  char* ws = (char*)d_ws;
  unsigned short* xbp   = (unsigned short*)(ws + WS_XB);
  unsigned short* w0tp  = (unsigned short*)(ws + WS_W0T);
  unsigned short* w1tp  = (unsigned short*)(ws + WS_W1T);
  unsigned short* ring0 = (unsigned short*)(ws + WS_RING0);
  unsigned short* ring1 = (unsigned short*)(ws + WS_RING1);
  unsigned*       barp  = (unsigned*)(ws + WS_BAR);

  // prep
  sentinel_kernel<<<dim3(1), dim3(1), 0, stream>>>(outp);
  convert_x_kernel<<<dim3(16384), dim3(256), 0, stream>>>(x, xbp);
  transpose_weights_kernel<<<dim3(48, 128), dim3(32, 8), 0, stream>>>(Wx0, Wh0, w0tp, 512, 1536);
  transpose_weights_kernel<<<dim3(64, 128), dim3(32, 8), 0, stream>>>(Wx1, Wh1, w1tp, 1024, 2048);
  // zero the t=-1 slots (slot 31 of each ring) + barrier counters
  hipMemsetAsync(ring0 + 31 * SLOT_ELEMS, 0, SLOT_BYTES, stream);
  hipMemsetAsync(ring1 + 31 * SLOT_ELEMS, 0, SLOT_BYTES, stream);
  hipMemsetAsync(barp, 0, 4096, stream);

  // persistent fused kernel; prefer cooperative launch, fall back to a plain
  // launch (256 blocks x 1 block/CU is co-resident on 256 CUs) if it fails.
  void* kargs[] = { (void*)&xbp, (void*)&w0tp, (void*)&w1tp, (void*)&b0, (void*)&b1,
                    (void*)&ring0, (void*)&ring1, (void*)&barp, (void*)&outp };
  hipError_t e = hipLaunchCooperativeKernel((void*)lstm_persistent, dim3(256), dim3(256),
                                            kargs, 32 * 2056 * 2 /* 131,584 B LDS */, stream);
  if (e != hipSuccess) {
    lstm_persistent<<<dim3(256), dim3(256), 32 * 2056 * 2, stream>>>(
        xbp, w0tp, w1tp, b0, b1, ring0, ring1, barp, outp);
  }
}